// Round 9
// baseline (317.460 us; speedup 1.0000x reference)
//
#include <hip/hip_runtime.h>
#include <hip/hip_bf16.h>
#include <stdint.h>

#define KDIM 512
#define OUT_F 512
#define MROWS 32         // rows per mtile
#define NMT 16           // mtiles per persistent block
#define NTHREADS 512     // 8 waves = 8 col-slices of 64

typedef __attribute__((ext_vector_type(8))) short short8;
typedef __attribute__((ext_vector_type(4))) float floatx4;

__device__ __forceinline__ ushort f2bf(float f) {
  uint32_t u = __builtin_bit_cast(uint32_t, f);
  uint32_t r = u + 0x7fffu + ((u >> 16) & 1u);   // RNE bf16
  return (ushort)(r >> 16);
}

#define LGKM0   asm volatile("s_waitcnt lgkmcnt(0)" ::: "memory")
#define FENCE   __builtin_amdgcn_sched_barrier(0)
#define SBAR    __builtin_amdgcn_s_barrier()

// ---------------------------------------------------------------------------
// Prep: W_eff (512x512) bf16 emitted DIRECTLY in MFMA B-fragment order:
//   addr = ((wc*16 + s)*4 + n)*512 + l*8 + e   (wc=wave col-slice, s=k-step,
//   n=16-col tile, l=lane, e=elem)  ->  col = wc*64+n*16+(l&15),
//   k = s*32+(l>>4)*8+e.  GEMM loads these as 64 coalesced 16B/lane reads.
// ---------------------------------------------------------------------------
__global__ void quat_prep_kernel(const float* __restrict__ wr, const float* __restrict__ wi,
                                 const float* __restrict__ wj, const float* __restrict__ wk,
                                 ushort* __restrict__ Bfrag) {
  int idx = blockIdx.x * 256 + threadIdx.x;
  if (idx >= 512 * 512) return;
  int e = idx & 7;
  int l = (idx >> 3) & 63;
  int n = (idx >> 9) & 3;
  int s = (idx >> 11) & 15;
  int wc = (idx >> 15) & 7;
  int col = wc * 64 + n * 16 + (l & 15);
  int k   = s * 32 + (l >> 4) * 8 + e;
  int og = col >> 7, o = col & 127, cg = k >> 7, c = k & 127;
  static const int   blkT[16] = {0,1,2,3, 1,0,3,2, 2,3,0,1, 3,2,1,0};
  static const float sgnT[16] = {1.f,-1.f,-1.f,-1.f, 1.f,1.f,1.f,-1.f,
                                 1.f,-1.f,1.f,1.f,   1.f,1.f,-1.f,1.f};
  int sel = og * 4 + cg;
  const float* Ws;
  switch (blkT[sel]) {
    case 0: Ws = wr; break;
    case 1: Ws = wi; break;
    case 2: Ws = wj; break;
    default: Ws = wk; break;
  }
  Bfrag[idx] = f2bf(sgnT[sel] * Ws[o * 128 + c]);
}

// ---------------------------------------------------------------------------
// GEMM: out[M,512] = X[M,512] * W_eff^T (+bias)
// Persistent streaming kernel: W_eff entirely in REGISTERS (128 VGPR/lane,
// loaded once from L2). 256 blocks (1/CU), each owns 512 contiguous rows.
// Per 32-row mtile: one linear 64KB X burst -> regs -> bf16 -> swizzled LDS
// (double-buffered), 128 MFMA/wave, scalar stores. ONE raw barrier per
// mtile, no vmcnt drain anywhere in the loop.
// ---------------------------------------------------------------------------
__global__ void __launch_bounds__(NTHREADS, 2)
quat_gemm_kernel(const float* __restrict__ X, const ushort* __restrict__ Bfrag,
                 const float* __restrict__ bias, float* __restrict__ Out) {
  __shared__ __align__(16) ushort As[2][MROWS * KDIM];   // 2 x 32 KB

  const int bid = blockIdx.x;                 // 256 blocks, 1 per CU
  const size_t row0 = (size_t)bid * (MROWS * NMT);
  const int tid = threadIdx.x, lane = tid & 63, wid = tid >> 6;
  const int lrow = lane & 15;
  const int lg   = lane >> 4;

  // ---- B fragments -> registers (issued first; oldest vmem) ----
  short8 breg[16][4];
#pragma unroll
  for (int s = 0; s < 16; ++s)
#pragma unroll
    for (int n = 0; n < 4; ++n)
      breg[s][n] = *reinterpret_cast<const short8*>(
          Bfrag + (((wid * 16 + s) * 4 + n) << 9) + lane * 8);

  const float4* X4 = reinterpret_cast<const float4*>(X);
  float4 av[8];                               // one 64KB mtile burst (linear)

  auto issueA = [&](int t) {
    size_t base = (row0 + (size_t)t * MROWS) * (KDIM / 4);
#pragma unroll
    for (int i = 0; i < 8; ++i)
      av[i] = X4[base + i * 512 + tid];
  };
  auto writeA = [&](ushort* Ab) {             // cvt + XOR-swizzled ds_write
#pragma unroll
    for (int i = 0; i < 8; ++i) {
      int f = i * 2048 + tid * 4;             // float index in 32x512 tile
      int row = f >> 9, col = f & 511;
      ushort4 o4;
      o4.x = f2bf(av[i].x); o4.y = f2bf(av[i].y);
      o4.z = f2bf(av[i].z); o4.w = f2bf(av[i].w);
      *reinterpret_cast<ushort4*>(Ab + row * KDIM + (col ^ ((row & 7) << 3))) = o4;
    }
  };

  float bval[4];
#pragma unroll
  for (int n = 0; n < 4; ++n) bval[n] = bias[wid * 64 + n * 16 + lrow];

  // ---- prologue ----
  issueA(0);
  writeA(As[0]);            // compiler inserts counted vmcnt for av (+B, bias)
  LGKM0; SBAR; FENCE;

#pragma unroll 1
  for (int t = 0; t < NMT; ++t) {
    const int cur = t & 1;
    if (t < NMT - 1) issueA(t + 1);           // linear burst, stays in flight

    floatx4 acc[2][4];
#pragma unroll
    for (int m = 0; m < 2; ++m)
#pragma unroll
      for (int n = 0; n < 4; ++n) acc[m][n] = {0.f, 0.f, 0.f, 0.f};

#pragma unroll
    for (int s = 0; s < 16; ++s) {
      short8 af[2];
#pragma unroll
      for (int m = 0; m < 2; ++m) {
        int row = m * 16 + lrow;
        int k = s * 32 + lg * 8;
        af[m] = *reinterpret_cast<const short8*>(
            &As[cur][row * KDIM + (k ^ ((row & 7) << 3))]);
      }
#pragma unroll
      for (int n = 0; n < 4; ++n) {
        acc[0][n] = __builtin_amdgcn_mfma_f32_16x16x32_bf16(af[0], breg[s][n], acc[0][n], 0, 0, 0);
        acc[1][n] = __builtin_amdgcn_mfma_f32_16x16x32_bf16(af[1], breg[s][n], acc[1][n], 0, 0, 0);
      }
    }

    // stores: 64B-sector-aligned scalar pattern (16 lanes x 4B contiguous)
    {
      float* Ob = Out + (row0 + (size_t)t * MROWS) * OUT_F;
#pragma unroll
      for (int n = 0; n < 4; ++n) {
        int col = wid * 64 + n * 16 + lrow;
#pragma unroll
        for (int m = 0; m < 2; ++m) {
          int rb = m * 16 + lg * 4;
#pragma unroll
          for (int j = 0; j < 4; ++j)
            Ob[(size_t)(rb + j) * OUT_F + col] = acc[m][n][j] + bval[n];
        }
      }
    }

    if (t < NMT - 1) {
      writeA(As[cur ^ 1]);  // counted vmcnt waits av only (stores younger)
      LGKM0; SBAR; FENCE;   // double-buffer => no other hazard, no vm drain
    }
  }
}

extern "C" void kernel_launch(void* const* d_in, const int* in_sizes, int n_in,
                              void* d_out, int out_size, void* d_ws, size_t ws_size,
                              hipStream_t stream) {
  const float* x    = (const float*)d_in[0];
  const float* wr   = (const float*)d_in[1];
  const float* wi   = (const float*)d_in[2];
  const float* wj   = (const float*)d_in[3];
  const float* wk   = (const float*)d_in[4];
  const float* bias = (const float*)d_in[5];
  float* out = (float*)d_out;
  ushort* Bfrag = (ushort*)d_ws;        // 512 KB

  int M = in_sizes[0] / KDIM;           // 131072
  int nwg = M / (MROWS * NMT);          // 256 persistent blocks

  hipLaunchKernelGGL(quat_prep_kernel, dim3((512 * 512 + 255) / 256), dim3(256), 0, stream,
                     wr, wi, wj, wk, Bfrag);
  hipLaunchKernelGGL(quat_gemm_kernel, dim3(nwg), dim3(NTHREADS), 0, stream,
                     x, Bfrag, bias, out);
}

// Round 10
// 149.996 us; speedup vs baseline: 2.1165x; 2.1165x over previous
//
#include <hip/hip_runtime.h>
#include <hip/hip_bf16.h>
#include <stdint.h>

#define KDIM 512
#define OUT_F 512
#define BM 128           // rows per block
#define BK 64            // k per step
#define NSTEP 8          // KDIM / BK
#define NTHREADS 1024    // 16 waves, 4M x 4N

typedef __attribute__((ext_vector_type(8))) short short8;
typedef __attribute__((ext_vector_type(4))) float floatx4;

__device__ __forceinline__ ushort f2bf(float f) {
  uint32_t u = __builtin_bit_cast(uint32_t, f);
  uint32_t r = u + 0x7fffu + ((u >> 16) & 1u);   // RNE bf16
  return (ushort)(r >> 16);
}

typedef const __attribute__((address_space(1))) uint32_t* gas1_u32;
typedef __attribute__((address_space(3))) uint32_t* gas3_u32;

__device__ __forceinline__ void gload_lds16(const void* g, void* l) {
  __builtin_amdgcn_global_load_lds((gas1_u32)g, (gas3_u32)l, 16, 0, 0);
}

#define VMCNT2  asm volatile("s_waitcnt vmcnt(2)" ::: "memory")
#define VMCNT0  asm volatile("s_waitcnt vmcnt(0)" ::: "memory")
#define LGKM0   asm volatile("s_waitcnt lgkmcnt(0)" ::: "memory")
#define FENCE   __builtin_amdgcn_sched_barrier(0)
#define SBAR    __builtin_amdgcn_s_barrier()

// ---------------------------------------------------------------------------
// Prep: W_eff (512x512) bf16 as [kt(8)][o(512)][k(64)] with XOR swizzle baked
// in; GEMM stages each 64KB kt-slab linearly via global_load_lds, reads
// swizzled (G21: source perm == read perm, dest linear).
// ---------------------------------------------------------------------------
__global__ void quat_prep_kernel(const float* __restrict__ wr, const float* __restrict__ wi,
                                 const float* __restrict__ wj, const float* __restrict__ wk,
                                 ushort* __restrict__ Bimg) {
  int idx = blockIdx.x * 256 + threadIdx.x;
  if (idx >= 512 * 512) return;
  int o = idx >> 9;        // output-feature index
  int c = idx & 511;       // input-feature index
  int og = o >> 7, oo = o & 127, cg = c >> 7, cc = c & 127;
  static const int   blkT[16] = {0,1,2,3, 1,0,3,2, 2,3,0,1, 3,2,1,0};
  static const float sgnT[16] = {1.f,-1.f,-1.f,-1.f, 1.f,1.f,1.f,-1.f,
                                 1.f,-1.f,1.f,1.f,   1.f,1.f,-1.f,1.f};
  int sel = og * 4 + cg;
  const float* Ws;
  switch (blkT[sel]) {
    case 0: Ws = wr; break;
    case 1: Ws = wi; break;
    case 2: Ws = wj; break;
    default: Ws = wk; break;
  }
  float v = sgnT[sel] * Ws[oo * 128 + cc];
  int kt = c >> 6, k = c & 63;
  int dst = kt * (OUT_F * BK) + o * BK + (k ^ ((o & 7) << 3));
  Bimg[dst] = f2bf(v);
}

// ---------------------------------------------------------------------------
// GEMM: out[M,512] = X[M,512] * W_eff^T (+bias)
// R7 structure: 128 rows x ALL 512 cols, BK=64 counted-vmcnt pipeline.
// ONE change vs R7: __launch_bounds__(1024,1) -> VGPR cap 128 (was 64 with
// arg=4, which spilled acc to scratch: +70MB WRITE, +FETCH, idle pipes).
// ---------------------------------------------------------------------------
__global__ void __launch_bounds__(NTHREADS, 1)
quat_gemm_kernel(const float* __restrict__ X, const ushort* __restrict__ Bimg,
                 const float* __restrict__ bias, float* __restrict__ Out) {
  __shared__ __align__(16) ushort As[2][BM * BK];      // 2 x 16 KB
  __shared__ __align__(16) ushort Bs[2][OUT_F * BK];   // 2 x 64 KB

  const int bid = blockIdx.x;
  const size_t row0 = (size_t)bid * BM;
  const int tid = threadIdx.x, lane = tid & 63, wid = tid >> 6;
  const int lrow = lane & 15;
  const int lg   = lane >> 4;
  const int wm = wid >> 2, wn = wid & 3;     // 4M x 4N wave grid

  const int ar = tid >> 3;                   // A row [0,128)
  const int ac = (tid & 7) * 8;              // A col [0,64) step 8

  float4 av[2][2];                           // 2-deep A prefetch, 8 floats each

  auto issueA = [&](int t, int p) {
    const float* s = X + (row0 + ar) * KDIM + t * BK + ac;
    av[p][0] = *reinterpret_cast<const float4*>(s);
    av[p][1] = *reinterpret_cast<const float4*>(s + 4);
  };
  auto writeA = [&](int p, ushort* Ab) {
    short8 o;
    o[0] = (short)f2bf(av[p][0].x); o[1] = (short)f2bf(av[p][0].y);
    o[2] = (short)f2bf(av[p][0].z); o[3] = (short)f2bf(av[p][0].w);
    o[4] = (short)f2bf(av[p][1].x); o[5] = (short)f2bf(av[p][1].y);
    o[6] = (short)f2bf(av[p][1].z); o[7] = (short)f2bf(av[p][1].w);
    *reinterpret_cast<short8*>(Ab + ar * BK + (ac ^ ((ar & 7) << 3))) = o;
  };
  auto stageB = [&](int t, ushort* Bb) {     // 64KB: 16 waves x 4KB
    const ushort* s = Bimg + t * (OUT_F * BK) + wid * 2048 + lane * 8;
    ushort* d = Bb + wid * 2048;
#pragma unroll
    for (int i = 0; i < 4; ++i)
      gload_lds16(s + i * 512, d + i * 512);
  };

  floatx4 acc[2][8];
#pragma unroll
  for (int m = 0; m < 2; ++m)
#pragma unroll
    for (int n = 0; n < 8; ++n) acc[m][n] = {0.f, 0.f, 0.f, 0.f};

  auto compute = [&](const ushort* Ab, const ushort* Bb) {
#pragma unroll
    for (int kh = 0; kh < 2; ++kh) {
      const int kb = kh * 32 + lg * 8;
      short8 af[2];
#pragma unroll
      for (int m = 0; m < 2; ++m) {
        int row = wm * 32 + m * 16 + lrow;
        af[m] = *reinterpret_cast<const short8*>(Ab + row * BK + (kb ^ ((row & 7) << 3)));
      }
#pragma unroll
      for (int n = 0; n < 8; ++n) {
        int col = wn * 128 + n * 16 + lrow;
        short8 bf = *reinterpret_cast<const short8*>(Bb + col * BK + (kb ^ ((col & 7) << 3)));
        acc[0][n] = __builtin_amdgcn_mfma_f32_16x16x32_bf16(af[0], bf, acc[0][n], 0, 0, 0);
        acc[1][n] = __builtin_amdgcn_mfma_f32_16x16x32_bf16(af[1], bf, acc[1][n], 0, 0, 0);
      }
    }
  };

  // ---- prologue ----
  issueA(0, 0);
  stageB(0, Bs[0]);
  issueA(1, 1);
  writeA(0, As[0]);        // compiler inserts counted wait for A(0) regs
  VMCNT2; FENCE;           // B(0) in LDS; A(1) stays in flight
  LGKM0; SBAR;

  // ---- steady steps t = 0..5: stage B(t+1), prefetch A(t+2) ----
#define STEP_MAIN(T)                                        \
  {                                                         \
    stageB((T) + 1, Bs[((T) & 1) ^ 1]);                     \
    issueA((T) + 2, (T) & 1);                               \
    writeA(((T) + 1) & 1, (ushort*)As[((T) & 1) ^ 1]);      \
    compute(As[(T) & 1], Bs[(T) & 1]);                      \
    VMCNT2; FENCE;                                          \
    LGKM0; SBAR;                                            \
  }
  STEP_MAIN(0) STEP_MAIN(1) STEP_MAIN(2)
  STEP_MAIN(3) STEP_MAIN(4) STEP_MAIN(5)
#undef STEP_MAIN

  // t = 6: stage B(7), no A(8)
  {
    stageB(7, Bs[1]);
    writeA(1, (ushort*)As[1]);
    compute(As[0], Bs[0]);
    VMCNT0; FENCE;
    LGKM0; SBAR;
  }
  // t = 7: compute only
  compute(As[1], Bs[1]);

  // ---- epilogue: 128x512 fp32 tile, 64B-sector-aligned scalar stores ----
  float* Ob = Out + row0 * OUT_F;
#pragma unroll
  for (int n = 0; n < 8; ++n) {
    int col = wn * 128 + n * 16 + lrow;
    float bv = bias[col];
#pragma unroll
    for (int m = 0; m < 2; ++m) {
      int rbase = wm * 32 + m * 16 + lg * 4;
#pragma unroll
      for (int j = 0; j < 4; ++j)
        Ob[(size_t)(rbase + j) * OUT_F + col] = acc[m][n][j] + bv;
    }
  }
}

extern "C" void kernel_launch(void* const* d_in, const int* in_sizes, int n_in,
                              void* d_out, int out_size, void* d_ws, size_t ws_size,
                              hipStream_t stream) {
  const float* x    = (const float*)d_in[0];
  const float* wr   = (const float*)d_in[1];
  const float* wi   = (const float*)d_in[2];
  const float* wj   = (const float*)d_in[3];
  const float* wk   = (const float*)d_in[4];
  const float* bias = (const float*)d_in[5];
  float* out = (float*)d_out;
  ushort* Bimg = (ushort*)d_ws;         // 512 KB

  int M = in_sizes[0] / KDIM;           // 131072
  int nwg = M / BM;                     // 1024

  hipLaunchKernelGGL(quat_prep_kernel, dim3((512 * 512 + 255) / 256), dim3(256), 0, stream,
                     wr, wi, wj, wk, Bimg);
  hipLaunchKernelGGL(quat_gemm_kernel, dim3(nwg), dim3(NTHREADS), 0, stream,
                     x, Bimg, bias, out);
}